// Round 6
// baseline (181.662 us; speedup 1.0000x reference)
//
#include <hip/hip_runtime.h>
#include <hip/hip_bf16.h>
#include <cstdint>
#include <cstddef>

// Problem constants (from reference)
#define F0v   2048
#define F1v   2304
#define F2v   2560
#define E1v   256
#define E2v   256
#define BROWS 8192
#define ODIM  1024
#define NNZv  262144
#define NBv   1024

typedef __bf16 bf16x8 __attribute__((ext_vector_type(8)));
typedef float floatx4 __attribute__((ext_vector_type(4)));

__device__ __forceinline__ unsigned short f2bf(float f) {
  unsigned int u = __float_as_uint(f);
  u += 0x7FFFu + ((u >> 16) & 1u);   // round-to-nearest-even
  return (unsigned short)(u >> 16);
}

__device__ __forceinline__ void async_ld16(const void* g, void* l) {
  __builtin_amdgcn_global_load_lds(
      (const __attribute__((address_space(1))) unsigned int*)g,
      (__attribute__((address_space(3))) unsigned int*)l, 16, 0, 0);
}

// ---------------------------------------------------------------------------
// Kernel 1 (fused pre): 512-thread blocks.
//   blocks [0, 512):    COO scatter-add (atomics) — launched first so the
//                       atomic long-tail interleaves with row blocks.
//   blocks [512, 4608): h construction, TWO rows per block (half-block each).
// vs round-0 (1 row / 256-thr block): one table fold + one barrier per 2
// rows instead of per row, 16 KB payload per block — halves the dominant
// per-row overheads. Numerics identical (same fold, same f2bf, same order).
// Gathers stay LDS-served (global-gather variant regressed, r1: +24 MB HBM).
// LDS 22 KB/block -> 4 blocks/CU (wave-capped, 32 waves).
// ---------------------------------------------------------------------------
#define PREROWBLKS (BROWS / 2)     // 4096
#define PRESCATBLKS (NNZv / 512)   // 512

__global__ __launch_bounds__(512) void fused_pre_kernel(
    const float* __restrict__ x, const float* __restrict__ e1w,
    const float* __restrict__ e2w, const int* __restrict__ e1p,
    const int* __restrict__ e2p, unsigned short* __restrict__ h,
    const int* __restrict__ wr, const int* __restrict__ wc,
    const float* __restrict__ wv, const int* __restrict__ bidx,
    const float* __restrict__ bv, float* __restrict__ Wd,
    float* __restrict__ bias) {
  __shared__ float xrow[2][F0v];          // 16 KB
  __shared__ int   tsrc[E1v + E2v];       // 2 KB
  __shared__ float twa[E1v + E2v];        // 2 KB
  __shared__ float twb[E1v + E2v];        // 2 KB
  const int tid = threadIdx.x;

  if (blockIdx.x < PRESCATBLKS) {         // scatter blocks first
    int gid = blockIdx.x * 512 + tid;
    atomicAdd(&Wd[(size_t)wr[gid] * F2v + wc[gid]], wv[gid]);
    if (gid < NBv)
      atomicAdd(&bias[bidx[gid]], bv[gid]);
    return;
  }

  // Table fold: thread e handles entry e (512 threads, 512 entries).
  {
    int e = tid;
    if (e < E1v) {
      tsrc[e] = e1p[e]; twa[e] = e1w[e]; twb[e] = 1.0f;
    } else {
      int q = e - E1v;
      int p2 = e2p[q]; float w2 = e2w[q];
      if (p2 < F0v) { tsrc[e] = p2;        twa[e] = w2;     twb[e] = 1.0f; }
      else { int q1 = p2 - F0v; tsrc[e] = e1p[q1]; twa[e] = e1w[q1]; twb[e] = w2; }
    }
  }

  const int half = tid >> 8;              // 0..1: which row of the pair
  const int t    = tid & 255;             // 0..255 within the half
  const int row  = (blockIdx.x - PRESCATBLKS) * 2 + half;
  const float* xr = x + (size_t)row * F0v;
  unsigned short* hr = h + (size_t)row * F2v;

  // Main copy: each half-block streams its row (2 float4/thread), stages f32
  // in LDS for the gather phase, writes the bf16 main copy.
  float4 v0 = ((const float4*)xr)[t * 2];
  float4 v1 = ((const float4*)xr)[t * 2 + 1];
  ((float4*)xrow[half])[t * 2] = v0;
  ((float4*)xrow[half])[t * 2 + 1] = v1;
  union { unsigned short us[8]; uint4 u4; } pk;
  pk.us[0] = f2bf(v0.x); pk.us[1] = f2bf(v0.y);
  pk.us[2] = f2bf(v0.z); pk.us[3] = f2bf(v0.w);
  pk.us[4] = f2bf(v1.x); pk.us[5] = f2bf(v1.y);
  pk.us[6] = f2bf(v1.z); pk.us[7] = f2bf(v1.w);
  ((uint4*)hr)[t] = pk.u4;
  __syncthreads();

  // Embed tail: thread t of each half handles entries {2t, 2t+1} of its row.
  int j0 = t * 2;
  float a0 = fmaxf(fmaxf(xrow[half][tsrc[j0]] * twa[j0], 0.0f) * twb[j0], 0.0f);
  float a1 = fmaxf(fmaxf(xrow[half][tsrc[j0 + 1]] * twa[j0 + 1], 0.0f) * twb[j0 + 1], 0.0f);
  unsigned int packed = (unsigned int)f2bf(a0) | ((unsigned int)f2bf(a1) << 16);
  ((unsigned int*)(hr + F0v))[t] = packed;
}

// ---------------------------------------------------------------------------
// Kernel 2: W f32 -> bf16 (8 elems/thread)
// ---------------------------------------------------------------------------
__global__ __launch_bounds__(256) void convert_kernel(
    const float* __restrict__ Wd, unsigned short* __restrict__ Wb) {
  int gid = blockIdx.x * 256 + threadIdx.x;
  const float4* src = (const float4*)Wd;
  float4 a = src[gid * 2];
  float4 b = src[gid * 2 + 1];
  union { unsigned short us[8]; uint4 u4; } pk;
  pk.us[0] = f2bf(a.x); pk.us[1] = f2bf(a.y);
  pk.us[2] = f2bf(a.z); pk.us[3] = f2bf(a.w);
  pk.us[4] = f2bf(b.x); pk.us[5] = f2bf(b.y);
  pk.us[6] = f2bf(b.z); pk.us[7] = f2bf(b.w);
  ((uint4*)Wb)[gid] = pk.u4;
}

// ---------------------------------------------------------------------------
// Kernel 3: C = h @ W^T + bias.  BEST-MEASURED VERSION (46.1 µs, round-3
// bench): 8-phase counted-vmcnt schedule, BM=256 x BN=128, BK=64, 512 thr
// (8 waves, 4M x 2N), triple-buffered LDS (3 x 48 KB), XCD-aware decode
// (FETCH 41 MB verified). Subsequent variants (barrier-free dataflow 47.5,
// cross-window reg pipelining 50.6) regressed — plateau ~46 µs at MfmaUtil
// ~34%; reverted to this and frozen.
// ---------------------------------------------------------------------------
#define BM 256
#define BN 128
#define BK 64
#define NT 40                 // K-tiles = F2v / BK
#define BUFE 24576            // elems per buffer: (256+128)*64
#define AOFF 16384            // B-matrix offset within buffer (elems)

#define STA(t, buf, u) \
  async_ld16(gA + (size_t)(u) * 64 * F2v + (t) * BK, \
             &lds[(buf) * BUFE + (u) * 4096 + tid * 8])
#define STB(t, buf, u) \
  async_ld16(gB + (size_t)(u) * 64 * F2v + (t) * BK, \
             &lds[(buf) * BUFE + AOFF + (u) * 4096 + tid * 8])

#define LDA(buf, mi, kk) \
  (*(const bf16x8*)&lds[(buf) * BUFE + rowA[mi] + segq[kk]])
#define LDB(buf, ni, kk) \
  (*(const bf16x8*)&lds[(buf) * BUFE + AOFF + rowB[ni] + segq[kk]])

#define MF(mi, ni) \
  acc[mi][ni] = __builtin_amdgcn_mfma_f32_16x16x32_bf16(af[mi][0], bfr[ni][0], acc[mi][ni], 0, 0, 0); \
  acc[mi][ni] = __builtin_amdgcn_mfma_f32_16x16x32_bf16(af[mi][1], bfr[ni][1], acc[mi][ni], 0, 0, 0);

#define BAR() __builtin_amdgcn_s_barrier()
#define PRIO1() __builtin_amdgcn_s_setprio(1)
#define PRIO0() __builtin_amdgcn_s_setprio(0)

__global__ __launch_bounds__(512, 2) void gemm_bt_kernel(
    const unsigned short* __restrict__ A,
    const unsigned short* __restrict__ Bw,
    const float* __restrict__ bias,
    float* __restrict__ C) {
  extern __shared__ unsigned short lds[];
  const int tid  = threadIdx.x;
  const int wave = tid >> 6;      // 0..7
  const int lane = tid & 63;
  const int wm = wave >> 1;       // 0..3 (64-row quarter of M)
  const int wn = wave & 1;        // 0..1 (64-col half of N)
  const int quad = lane >> 4;     // 0..3
  const int r16 = lane & 15;
  const int r7 = r16 & 7;

  // XCD-aware decode: 256 blocks, id%8 = XCD. XCD k owns M-tiles [4k,4k+4)
  // x all 8 N-tiles (32 blocks = its 32 CUs, 1 block/CU).
  const int id  = blockIdx.y * 8 + blockIdx.x;
  const int xcd = id & 7;
  const int j   = id >> 3;                  // 0..31 within XCD
  const int m0 = (xcd * 4 + (j & 3)) * BM;  // M-tile 0..31
  const int n0 = (j >> 2) * BN;             // N-tile 0..7

  // Staging: call = 64-row unit (8 KB = 512 thr x 16 B). Thread tid: row
  // tid/8 within unit, stored seg tid%8, sourcing global seg (tid%8)^(row&7)
  // (pre-swizzled source, linear LDS dest = wave-uniform base + lane*16).
  const int srow = tid >> 3;                       // 0..63
  const int sseg8 = ((tid & 7) ^ (srow & 7)) * 8;
  const unsigned short* gA = A  + (size_t)(m0 + srow) * F2v + sseg8;
  const unsigned short* gB = Bw + (size_t)(n0 + srow) * F2v + sseg8;

  // Frag-read invariants; read seg = (kk*4+quad)^(row&7), row&7 == r16&7.
  int rowA[4], rowB[4], segq[2];
#pragma unroll
  for (int i = 0; i < 4; ++i) {
    rowA[i] = (wm * 64 + i * 16 + r16) * 64;
    rowB[i] = (wn * 64 + i * 16 + r16) * 64;
  }
  segq[0] = ((quad) ^ r7) * 8;
  segq[1] = ((4 + quad) ^ r7) * 8;

  floatx4 acc[4][4];
  floatx4 zz = {0.f, 0.f, 0.f, 0.f};
#pragma unroll
  for (int i = 0; i < 4; ++i)
#pragma unroll
    for (int j2 = 0; j2 < 4; ++j2) acc[i][j2] = zz;

  bf16x8 af[4][2], bfr[4][2];

  // Prologue: stage tiles 0 -> buf0, 1 -> buf1 (6 calls each)
#pragma unroll
  for (int u = 0; u < 4; ++u) STA(0, 0, u);
  STB(0, 0, 0); STB(0, 0, 1);
#pragma unroll
  for (int u = 0; u < 4; ++u) STA(1, 1, u);
  STB(1, 1, 0); STB(1, 1, 1);
  asm volatile("s_waitcnt vmcnt(6)" ::: "memory");  // tile 0 landed
  BAR();

  int c0 = 0, c1 = 1, c2 = 2;   // buffers of tiles 2i, 2i+1, 2i+2
  for (int i = 0; i < 20; ++i) {
    const int t2 = 2 * i + 2, t3 = 2 * i + 3;
    const bool s2 = t2 < NT, s3 = t3 < NT;

    // ===== K-tile t0 = 2i  (buffer c0) =====
    // ph1 (m01,n01)
    af[0][0] = LDA(c0, 0, 0); af[0][1] = LDA(c0, 0, 1);
    af[1][0] = LDA(c0, 1, 0); af[1][1] = LDA(c0, 1, 1);
    bfr[0][0] = LDB(c0, 0, 0); bfr[0][1] = LDB(c0, 0, 1);
    bfr[1][0] = LDB(c0, 1, 0); bfr[1][1] = LDB(c0, 1, 1);
    if (s2) { STA(t2, c2, 0); STA(t2, c2, 1); }
    BAR();
    PRIO1(); MF(0, 0) MF(0, 1) MF(1, 0) MF(1, 1) PRIO0();
    BAR();
    // ph2 (m23,n01)
    af[2][0] = LDA(c0, 2, 0); af[2][1] = LDA(c0, 2, 1);
    af[3][0] = LDA(c0, 3, 0); af[3][1] = LDA(c0, 3, 1);
    if (s2) { STA(t2, c2, 2); STA(t2, c2, 3); }
    BAR();
    PRIO1(); MF(2, 0) MF(2, 1) MF(3, 0) MF(3, 1) PRIO0();
    BAR();
    // ph3 (m01,n23)
    bfr[2][0] = LDB(c0, 2, 0); bfr[2][1] = LDB(c0, 2, 1);
    bfr[3][0] = LDB(c0, 3, 0); bfr[3][1] = LDB(c0, 3, 1);
    if (s2) { STB(t2, c2, 0); STB(t2, c2, 1); }
    BAR();
    PRIO1(); MF(0, 2) MF(0, 3) MF(1, 2) MF(1, 3) PRIO0();
    BAR();
    // ph4 (m23,n23) — all frags cached
    PRIO1(); MF(2, 2) MF(2, 3) MF(3, 2) MF(3, 3) PRIO0();
    if (i < 19) asm volatile("s_waitcnt vmcnt(6)" ::: "memory");  // t1 landed
    else        asm volatile("s_waitcnt vmcnt(0)" ::: "memory");
    BAR();

    // ===== K-tile t1 = 2i+1  (buffer c1) =====
    // t3 -> buffer c0: old data (t0) fully ds_read by ph3's barrier.
    // ph5
    af[0][0] = LDA(c1, 0, 0); af[0][1] = LDA(c1, 0, 1);
    af[1][0] = LDA(c1, 1, 0); af[1][1] = LDA(c1, 1, 1);
    bfr[0][0] = LDB(c1, 0, 0); bfr[0][1] = LDB(c1, 0, 1);
    bfr[1][0] = LDB(c1, 1, 0); bfr[1][1] = LDB(c1, 1, 1);
    if (s3) { STA(t3, c0, 0); STA(t3, c0, 1); }
    BAR();
    PRIO1(); MF(0, 0) MF(0, 1) MF(1, 0) MF(1, 1) PRIO0();
    BAR();
    // ph6
    af[2][0] = LDA(c1, 2, 0); af[2][1] = LDA(c1, 2, 1);
    af[3][0] = LDA(c1, 3, 0); af[3][1] = LDA(c1, 3, 1);
    if (s3) { STA(t3, c0, 2); STA(t3, c0, 3); }
    BAR();
    PRIO1(); MF(2, 0) MF(2, 1) MF(3, 0) MF(3, 1) PRIO0();
    BAR();
    // ph7
    bfr[2][0] = LDB(c1, 2, 0); bfr[2][1] = LDB(c1, 2, 1);
    bfr[3][0] = LDB(c1, 3, 0); bfr[3][1] = LDB(c1, 3, 1);
    if (s3) { STB(t3, c0, 0); STB(t3, c0, 1); }
    BAR();
    PRIO1(); MF(0, 2) MF(0, 3) MF(1, 2) MF(1, 3) PRIO0();
    BAR();
    // ph8
    PRIO1(); MF(2, 2) MF(2, 3) MF(3, 2) MF(3, 3) PRIO0();
    if (i < 19) asm volatile("s_waitcnt vmcnt(6)" ::: "memory");  // t2 landed
    BAR();

    // rotate buffers: tiles (2i+2, 2i+3, 2i+4) -> (c2, c0, c1)
    int tmp = c0; c0 = c2; c2 = c1; c1 = tmp;
  }

  // Epilogue: C/D layout col = lane&15, row = quad*4 + reg (m89/m91 verified)
#pragma unroll
  for (int ni = 0; ni < 4; ++ni) {
    int col = n0 + wn * 64 + ni * 16 + r16;
    float bc = bias[col];
#pragma unroll
    for (int mi = 0; mi < 4; ++mi) {
      int row = m0 + wm * 64 + mi * 16 + quad * 4;
#pragma unroll
      for (int rg = 0; rg < 4; ++rg)
        C[(size_t)(row + rg) * ODIM + col] = acc[mi][ni][rg] + bc;
    }
  }
}

// ---------------------------------------------------------------------------
extern "C" void kernel_launch(void* const* d_in, const int* in_sizes, int n_in,
                              void* d_out, int out_size, void* d_ws, size_t ws_size,
                              hipStream_t stream) {
  const float* x    = (const float*)d_in[0];
  const float* e1w  = (const float*)d_in[1];
  const float* e2w  = (const float*)d_in[2];
  const float* wv   = (const float*)d_in[3];
  const float* bv   = (const float*)d_in[4];
  const int*   e1p  = (const int*)d_in[5];
  const int*   e2p  = (const int*)d_in[6];
  const int*   wr   = (const int*)d_in[7];
  const int*   wc   = (const int*)d_in[8];
  const int*   bidx = (const int*)d_in[9];
  float* out = (float*)d_out;

  // Workspace carve (total ~57.7 MB)
  char* ws = (char*)d_ws;
  const size_t h_bytes  = (size_t)BROWS * F2v * 2;        // 41,943,040
  const size_t wd_bytes = (size_t)ODIM * F2v * 4;         // 10,485,760
  const size_t b_bytes  = (size_t)ODIM * 4;               // 4,096
  unsigned short* h   = (unsigned short*)ws;
  float* Wd           = (float*)(ws + h_bytes);
  float* bias         = (float*)(ws + h_bytes + wd_bytes);
  unsigned short* Wb  = (unsigned short*)(ws + h_bytes + wd_bytes + b_bytes);

  hipMemsetAsync(Wd, 0, wd_bytes + b_bytes, stream);
  fused_pre_kernel<<<PRESCATBLKS + PREROWBLKS, 512, 0, stream>>>(
      x, e1w, e2w, e1p, e2p, h, wr, wc, wv, bidx, bv, Wd, bias);
  convert_kernel<<<(ODIM * F2v / 8) / 256, 256, 0, stream>>>(Wd, Wb);

  // 144 KB dynamic LDS (3 x 48 KB triple buffer)
  hipFuncSetAttribute(reinterpret_cast<const void*>(gemm_bt_kernel),
                      hipFuncAttributeMaxDynamicSharedMemorySize, 3 * BUFE * 2);
  gemm_bt_kernel<<<dim3(ODIM / BN, BROWS / BM), 512, 3 * BUFE * 2, stream>>>(
      h, Wb, bias, out);
}